// Round 1
// baseline (451.336 us; speedup 1.0000x reference)
//
#include <hip/hip_runtime.h>
#include <cstdint>
#include <cstddef>

#define NPTS 16384
#define KSEL 4096
#define HIDDEN 128
#define NHEADS 8
#define DHEAD 16
#define OUTD 256

// ---- workspace layout (bytes), all offsets multiple of 1024 ----
constexpr size_t OFF_CENTER = 0;                          // 4 floats
constexpr size_t OFF_PX  = 1024;                          // NPTS f32
constexpr size_t OFF_PY  = OFF_PX  + (size_t)NPTS*4;
constexpr size_t OFF_PZ  = OFF_PY  + (size_t)NPTS*4;
constexpr size_t OFF_SQ  = OFF_PZ  + (size_t)NPTS*4;
constexpr size_t OFF_DL  = OFF_SQ  + (size_t)NPTS*4;
constexpr size_t OFF_CNT = OFF_DL  + (size_t)NPTS*4;      // int
constexpr size_t OFF_KEY = OFF_CNT + (size_t)NPTS*4;      // uint
constexpr size_t OFF_SEL = OFF_KEY + (size_t)NPTS*4;      // KSEL int
constexpr size_t OFF_Q   = OFF_SEL + (size_t)KSEL*4;      // KSEL*128 f32 (pre-scaled by log2e/4)
constexpr size_t OFF_K   = OFF_Q   + (size_t)KSEL*HIDDEN*4;
constexpr size_t OFF_V   = OFF_K   + (size_t)KSEL*HIDDEN*4;
constexpr size_t OFF_LP  = OFF_V   + (size_t)KSEL*HIDDEN*4;  // 8*4096*16 f32 partial l
constexpr size_t OFF_RL  = OFF_LP  + (size_t)NHEADS*KSEL*16*4; // 8*4096 f32 1/l
constexpr size_t OFF_W   = OFF_RL  + (size_t)NHEADS*KSEL*4;    // 8*4096 f32 col weights
constexpr size_t OFF_PAV = OFF_W   + (size_t)NHEADS*KSEL*4;    // 128 f32 pooled av

__device__ __forceinline__ float dot16(const float4& a0, const float4& a1, const float4& a2, const float4& a3,
                                       const float4& b0, const float4& b1, const float4& b2, const float4& b3) {
    float p0 = fmaf(a0.x, b0.x, a0.y * b0.y); p0 = fmaf(a0.z, b0.z, p0); p0 = fmaf(a0.w, b0.w, p0);
    float p1 = fmaf(a1.x, b1.x, a1.y * b1.y); p1 = fmaf(a1.z, b1.z, p1); p1 = fmaf(a1.w, b1.w, p1);
    float p2 = fmaf(a2.x, b2.x, a2.y * b2.y); p2 = fmaf(a2.z, b2.z, p2); p2 = fmaf(a2.w, b2.w, p2);
    float p3 = fmaf(a3.x, b3.x, a3.y * b3.y); p3 = fmaf(a3.z, b3.z, p3); p3 = fmaf(a3.w, b3.w, p3);
    return (p0 + p1) + (p2 + p3);
}

// ---- 1. ligand center ----
__global__ void k_center(const float* __restrict__ lp, int M, float* __restrict__ center) {
    int t = threadIdx.x; // 64 threads
    float x = 0.f, y = 0.f, z = 0.f;
    for (int i = t; i < M; i += 64) { x += lp[i*3+0]; y += lp[i*3+1]; z += lp[i*3+2]; }
    for (int o = 32; o > 0; o >>= 1) { x += __shfl_down(x, o); y += __shfl_down(y, o); z += __shfl_down(z, o); }
    if (t == 0) { float m = (float)M; center[0] = x/m; center[1] = y/m; center[2] = z/m; }
}

// ---- 2. SoA pos + sq + d_lig ----
__global__ void k_prep(const float* __restrict__ pos, const float* __restrict__ center,
                       float* __restrict__ px, float* __restrict__ py, float* __restrict__ pz,
                       float* __restrict__ sq, float* __restrict__ dl) {
    int i = blockIdx.x * blockDim.x + threadIdx.x;
    float x = pos[i*3+0], y = pos[i*3+1], z = pos[i*3+2];
    px[i] = x; py[i] = y; pz[i] = z;
    sq[i] = (x*x + y*y) + z*z;
    float dx = x - center[0], dy = y - center[1], dz = z - center[2];
    dl[i] = sqrtf((dx*dx + dy*dy) + dz*dz);
}

// ---- 3. neighbor counts (includes self; compensated in score) ----
__global__ void __launch_bounds__(256) k_neighbor(const float* __restrict__ px, const float* __restrict__ py,
                                                  const float* __restrict__ pz, const float* __restrict__ sq,
                                                  int* __restrict__ cnt) {
    __shared__ float4 xt[256], yt[256], zt[256], st[256];
    int tid = threadIdx.x;
    int i = blockIdx.x * 256 + tid;
    float xi = px[i], yi = py[i], zi = pz[i], si = sq[i];
    int c = 0;
    int jbase = blockIdx.y * 2048;
    for (int t0 = 0; t0 < 2; t0++) {
        int j0 = jbase + t0 * 1024;
        __syncthreads();
        xt[tid] = ((const float4*)(px + j0))[tid];
        yt[tid] = ((const float4*)(py + j0))[tid];
        zt[tid] = ((const float4*)(pz + j0))[tid];
        st[tid] = ((const float4*)(sq + j0))[tid];
        __syncthreads();
        for (int t = 0; t < 256; t++) {
            float4 xj = xt[t], yj = yt[t], zj = zt[t], sj = st[t];
            { float dot = fmaf(xi, xj.x, fmaf(yi, yj.x, zi*zj.x)); float d2 = (si + sj.x) - 2.0f*dot; c += (d2 < 9.0f); }
            { float dot = fmaf(xi, xj.y, fmaf(yi, yj.y, zi*zj.y)); float d2 = (si + sj.y) - 2.0f*dot; c += (d2 < 9.0f); }
            { float dot = fmaf(xi, xj.z, fmaf(yi, yj.z, zi*zj.z)); float d2 = (si + sj.z) - 2.0f*dot; c += (d2 < 9.0f); }
            { float dot = fmaf(xi, xj.w, fmaf(yi, yj.w, zi*zj.w)); float d2 = (si + sj.w) - 2.0f*dot; c += (d2 < 9.0f); }
        }
    }
    atomicAdd(&cnt[i], c);
}

// ---- 4. scores -> monotonic sortable uint keys ----
__global__ void k_scores(const float* __restrict__ dl, const int* __restrict__ cnt,
                         unsigned int* __restrict__ keys) {
    int i = blockIdx.x * blockDim.x + threadIdx.x;
    // surface = 1/(nc+1), nc = cnt_with_self - 1  =>  1/cnt_with_self
    float score = 1.0f / (1.0f + dl[i] / 5.0f) + 0.5f * (1.0f / (float)cnt[i]);
    unsigned int u = __float_as_uint(score);
    keys[i] = u ^ ((u & 0x80000000u) ? 0xFFFFFFFFu : 0x80000000u);
}

// ---- 5. exact top-KSEL radix select (ties -> lowest index, matching lax.top_k) ----
__global__ void __launch_bounds__(1024) k_select(const unsigned int* __restrict__ keys, int* __restrict__ sel) {
    __shared__ unsigned int sk[NPTS];
    __shared__ int hist[256];
    __shared__ unsigned int s_prefix;
    __shared__ int s_rem, s_eqtot, s_nout, s_digit, s_cgt;
    int tid = threadIdx.x;
    for (int i = tid; i < NPTS; i += 1024) sk[i] = keys[i];
    if (tid == 0) { s_prefix = 0; s_rem = KSEL; s_nout = 0; s_eqtot = 0; }
    __syncthreads();
    for (int p = 0; p < 4; p++) {
        int sh = 24 - 8 * p;
        if (tid < 256) hist[tid] = 0;
        __syncthreads();
        unsigned int pref = s_prefix;
        int shp = (p == 0) ? 0 : (32 - 8 * p);
        for (int i = tid; i < NPTS; i += 1024) {
            unsigned int key = sk[i];
            bool m = (p == 0) || ((key >> shp) == pref);
            if (m) atomicAdd(&hist[(key >> sh) & 255], 1);
        }
        __syncthreads();
        int rem = s_rem;
        if (tid < 256) {
            int cg = 0;
            for (int d = tid + 1; d < 256; d++) cg += hist[d];
            if (cg < rem && cg + hist[tid] >= rem) { s_digit = tid; s_cgt = cg; }
        }
        __syncthreads();
        if (tid == 0) {
            s_prefix = (s_prefix << 8) | (unsigned int)s_digit;
            s_rem = rem - s_cgt;
            if (p == 3) s_eqtot = hist[s_digit];
        }
        __syncthreads();
    }
    unsigned int T = s_prefix;
    int need_eq = s_rem;
    for (int i = tid; i < NPTS; i += 1024)
        if (sk[i] > T) sel[atomicAdd(&s_nout, 1)] = i;
    __syncthreads();
    if (s_eqtot == need_eq) {
        for (int i = tid; i < NPTS; i += 1024)
            if (sk[i] == T) sel[atomicAdd(&s_nout, 1)] = i;
    } else {
        for (int i = tid; i < NPTS; i += 1024) {
            if (sk[i] == T) {
                int rank = 0;
                for (int j = 0; j < i; j++) rank += (sk[j] == T);
                if (rank < need_eq) sel[atomicAdd(&s_nout, 1)] = i;
            }
        }
    }
}

// ---- 6. gather + node embed + QKV projections (Q pre-scaled by log2e/4) ----
__global__ void __launch_bounds__(128) k_qkv(const float* __restrict__ x, const int* __restrict__ sel,
        const float* __restrict__ Wn, const float* __restrict__ bn,
        const float* __restrict__ Wq, const float* __restrict__ bq,
        const float* __restrict__ Wk, const float* __restrict__ bk,
        const float* __restrict__ Wv, const float* __restrict__ bv,
        float* __restrict__ qg, float* __restrict__ kg, float* __restrict__ vg) {
    __shared__ float xs[16][8];
    __shared__ __align__(16) float hs[16][HIDDEN];
    int d = threadIdx.x;
    int r0 = blockIdx.x * 16;
    { int rr = d >> 3, cc = d & 7; xs[rr][cc] = x[(size_t)sel[r0 + rr] * 8 + cc]; }
    __syncthreads();
    {
        float wn[8];
        #pragma unroll
        for (int c = 0; c < 8; c++) wn[c] = Wn[c * HIDDEN + d];
        float b = bn[d];
        #pragma unroll
        for (int r = 0; r < 16; r++) {
            float a = b;
            #pragma unroll
            for (int c = 0; c < 8; c++) a = fmaf(xs[r][c], wn[c], a);
            hs[r][d] = a;
        }
    }
    __syncthreads();
    float acc[16];
    // Q
    { float b = bq[d];
      #pragma unroll
      for (int r = 0; r < 16; r++) acc[r] = b;
      for (int c = 0; c < HIDDEN; c += 4) {
          float w0 = Wq[(c+0)*HIDDEN+d], w1 = Wq[(c+1)*HIDDEN+d], w2 = Wq[(c+2)*HIDDEN+d], w3 = Wq[(c+3)*HIDDEN+d];
          #pragma unroll
          for (int r = 0; r < 16; r++) {
              float4 h4 = *(const float4*)&hs[r][c];
              float a = acc[r];
              a = fmaf(h4.x, w0, a); a = fmaf(h4.y, w1, a); a = fmaf(h4.z, w2, a); a = fmaf(h4.w, w3, a);
              acc[r] = a;
          }
      }
      #pragma unroll
      for (int r = 0; r < 16; r++) qg[(size_t)(r0+r)*HIDDEN + d] = acc[r] * 0.36067376022224085f; // log2(e)/4
    }
    // K
    { float b = bk[d];
      #pragma unroll
      for (int r = 0; r < 16; r++) acc[r] = b;
      for (int c = 0; c < HIDDEN; c += 4) {
          float w0 = Wk[(c+0)*HIDDEN+d], w1 = Wk[(c+1)*HIDDEN+d], w2 = Wk[(c+2)*HIDDEN+d], w3 = Wk[(c+3)*HIDDEN+d];
          #pragma unroll
          for (int r = 0; r < 16; r++) {
              float4 h4 = *(const float4*)&hs[r][c];
              float a = acc[r];
              a = fmaf(h4.x, w0, a); a = fmaf(h4.y, w1, a); a = fmaf(h4.z, w2, a); a = fmaf(h4.w, w3, a);
              acc[r] = a;
          }
      }
      #pragma unroll
      for (int r = 0; r < 16; r++) kg[(size_t)(r0+r)*HIDDEN + d] = acc[r];
    }
    // V
    { float b = bv[d];
      #pragma unroll
      for (int r = 0; r < 16; r++) acc[r] = b;
      for (int c = 0; c < HIDDEN; c += 4) {
          float w0 = Wv[(c+0)*HIDDEN+d], w1 = Wv[(c+1)*HIDDEN+d], w2 = Wv[(c+2)*HIDDEN+d], w3 = Wv[(c+3)*HIDDEN+d];
          #pragma unroll
          for (int r = 0; r < 16; r++) {
              float4 h4 = *(const float4*)&hs[r][c];
              float a = acc[r];
              a = fmaf(h4.x, w0, a); a = fmaf(h4.y, w1, a); a = fmaf(h4.z, w2, a); a = fmaf(h4.w, w3, a);
              acc[r] = a;
          }
      }
      #pragma unroll
      for (int r = 0; r < 16; r++) vg[(size_t)(r0+r)*HIDDEN + d] = acc[r];
    }
}

// ---- 7. phase 1: l_q partials (sum over k-slice of 2^(q'.k)); no max needed (|s|<~10) ----
__global__ void __launch_bounds__(256) k_attn_l(const float* __restrict__ qg, const float* __restrict__ kg,
                                                float* __restrict__ lpart) {
    int ks = blockIdx.x, qt = blockIdx.y, h = blockIdx.z;
    int tid = threadIdx.x;
    __shared__ float4 kt[256][4];
    {
        const float4* src = (const float4*)(kg + ((size_t)(ks*256 + tid))*HIDDEN + h*DHEAD);
        kt[tid][0] = src[0]; kt[tid][1] = src[1]; kt[tid][2] = src[2]; kt[tid][3] = src[3];
    }
    int q0 = qt * 1024 + tid * 4;
    float4 qa[4][4];
    #pragma unroll
    for (int r = 0; r < 4; r++) {
        const float4* qs = (const float4*)(qg + ((size_t)(q0+r))*HIDDEN + h*DHEAD);
        qa[r][0] = qs[0]; qa[r][1] = qs[1]; qa[r][2] = qs[2]; qa[r][3] = qs[3];
    }
    __syncthreads();
    float l0 = 0.f, l1 = 0.f, l2 = 0.f, l3 = 0.f;
    for (int j = 0; j < 256; j++) {
        float4 k0 = kt[j][0], k1 = kt[j][1], k2 = kt[j][2], k3 = kt[j][3];
        l0 += exp2f(dot16(qa[0][0], qa[0][1], qa[0][2], qa[0][3], k0, k1, k2, k3));
        l1 += exp2f(dot16(qa[1][0], qa[1][1], qa[1][2], qa[1][3], k0, k1, k2, k3));
        l2 += exp2f(dot16(qa[2][0], qa[2][1], qa[2][2], qa[2][3], k0, k1, k2, k3));
        l3 += exp2f(dot16(qa[3][0], qa[3][1], qa[3][2], qa[3][3], k0, k1, k2, k3));
    }
    size_t base = ((size_t)h * KSEL + q0) * 16 + ks;
    lpart[base] = l0; lpart[base + 16] = l1; lpart[base + 32] = l2; lpart[base + 48] = l3;
}

// ---- 8. combine partials -> 1/l ----
__global__ void k_combine(const float* __restrict__ lpart, float* __restrict__ rl) {
    int i = blockIdx.x * 256 + threadIdx.x; // 32768 total
    const float4* p = (const float4*)(lpart + (size_t)i * 16);
    float4 a = p[0], b = p[1], c = p[2], d = p[3];
    float s = ((a.x + a.y) + (a.z + a.w)) + ((b.x + b.y) + (b.z + b.w))
            + ((c.x + c.y) + (c.z + c.w)) + ((d.x + d.y) + (d.z + d.w));
    rl[i] = 1.0f / s;
}

// ---- 9. phase 2: column weights w_j = sum_q 2^(q'.k) / l_q ----
__global__ void __launch_bounds__(256) k_attn_w(const float* __restrict__ qg, const float* __restrict__ kg,
                                                const float* __restrict__ rl, float* __restrict__ wg) {
    int qs = blockIdx.x, jt = blockIdx.y, h = blockIdx.z;
    int tid = threadIdx.x;
    __shared__ float4 qt4[256][4];
    __shared__ float rls[256];
    {
        const float4* src = (const float4*)(qg + ((size_t)(qs*256 + tid))*HIDDEN + h*DHEAD);
        qt4[tid][0] = src[0]; qt4[tid][1] = src[1]; qt4[tid][2] = src[2]; qt4[tid][3] = src[3];
        rls[tid] = rl[(size_t)h * KSEL + qs*256 + tid];
    }
    int j0 = jt * 1024 + tid * 4;
    float4 kk[4][4];
    #pragma unroll
    for (int c = 0; c < 4; c++) {
        const float4* src = (const float4*)(kg + ((size_t)(j0+c))*HIDDEN + h*DHEAD);
        kk[c][0] = src[0]; kk[c][1] = src[1]; kk[c][2] = src[2]; kk[c][3] = src[3];
    }
    __syncthreads();
    float w0 = 0.f, w1 = 0.f, w2 = 0.f, w3 = 0.f;
    for (int q = 0; q < 256; q++) {
        float4 a0 = qt4[q][0], a1 = qt4[q][1], a2 = qt4[q][2], a3 = qt4[q][3];
        float r = rls[q];
        w0 = fmaf(exp2f(dot16(kk[0][0], kk[0][1], kk[0][2], kk[0][3], a0, a1, a2, a3)), r, w0);
        w1 = fmaf(exp2f(dot16(kk[1][0], kk[1][1], kk[1][2], kk[1][3], a0, a1, a2, a3)), r, w1);
        w2 = fmaf(exp2f(dot16(kk[2][0], kk[2][1], kk[2][2], kk[2][3], a0, a1, a2, a3)), r, w2);
        w3 = fmaf(exp2f(dot16(kk[3][0], kk[3][1], kk[3][2], kk[3][3], a0, a1, a2, a3)), r, w3);
    }
    size_t base = (size_t)h * KSEL + j0;
    atomicAdd(&wg[base+0], w0); atomicAdd(&wg[base+1], w1);
    atomicAdd(&wg[base+2], w2); atomicAdd(&wg[base+3], w3);
}

// ---- 10. pooled_av[h*16+d] = (1/K) sum_j w_j * v[j][h*16+d] ----
__global__ void __launch_bounds__(256) k_colsum(const float* __restrict__ wg, const float* __restrict__ vg,
                                                float* __restrict__ pav) {
    int h = blockIdx.x >> 4, d = blockIdx.x & 15;
    int t = threadIdx.x;
    float acc = 0.f;
    for (int j = t; j < KSEL; j += 256)
        acc = fmaf(wg[(size_t)h * KSEL + j], vg[(size_t)j * HIDDEN + h * DHEAD + d], acc);
    __shared__ float red[256];
    red[t] = acc; __syncthreads();
    for (int s = 128; s > 0; s >>= 1) { if (t < s) red[t] += red[t + s]; __syncthreads(); }
    if (t == 0) pav[h * DHEAD + d] = red[0] * (1.0f / (float)KSEL);
}

// ---- 11. out-proj + pool MLP ----
__global__ void __launch_bounds__(256) k_final(const float* __restrict__ pav,
        const float* __restrict__ Wo, const float* __restrict__ bo,
        const float* __restrict__ W1, const float* __restrict__ b1,
        const float* __restrict__ W2, const float* __restrict__ b2,
        float* __restrict__ out) {
    __shared__ float sp[HIDDEN];
    __shared__ float st[OUTD];
    int t = threadIdx.x;
    if (t < HIDDEN) {
        float a = bo[t];
        for (int c = 0; c < HIDDEN; c++) a = fmaf(pav[c], Wo[c * HIDDEN + t], a);
        sp[t] = a;
    }
    __syncthreads();
    {
        float a = b1[t];
        for (int c = 0; c < HIDDEN; c++) a = fmaf(sp[c], W1[c * OUTD + t], a);
        st[t] = fmaxf(a, 0.f);
    }
    __syncthreads();
    {
        float o = b2[t];
        for (int c = 0; c < OUTD; c++) o = fmaf(st[c], W2[c * OUTD + t], o);
        out[t] = o;
    }
}

extern "C" void kernel_launch(void* const* d_in, const int* in_sizes, int n_in,
                              void* d_out, int out_size, void* d_ws, size_t ws_size,
                              hipStream_t stream) {
    (void)n_in; (void)out_size; (void)ws_size;
    const float* x   = (const float*)d_in[0];
    const float* pos = (const float*)d_in[1];
    const float* lig = (const float*)d_in[2];
    const float* Wn  = (const float*)d_in[3];
    const float* bn  = (const float*)d_in[4];
    const float* Wq  = (const float*)d_in[5];
    const float* bq  = (const float*)d_in[6];
    const float* Wk  = (const float*)d_in[7];
    const float* bk  = (const float*)d_in[8];
    const float* Wv  = (const float*)d_in[9];
    const float* bv  = (const float*)d_in[10];
    const float* Wo  = (const float*)d_in[11];
    const float* bo  = (const float*)d_in[12];
    const float* W1  = (const float*)d_in[13];
    const float* b1  = (const float*)d_in[14];
    const float* W2  = (const float*)d_in[15];
    const float* b2  = (const float*)d_in[16];
    int M = in_sizes[2] / 3;

    char* ws = (char*)d_ws;
    float*        center = (float*)(ws + OFF_CENTER);
    float*        px  = (float*)(ws + OFF_PX);
    float*        py  = (float*)(ws + OFF_PY);
    float*        pz  = (float*)(ws + OFF_PZ);
    float*        sq  = (float*)(ws + OFF_SQ);
    float*        dl  = (float*)(ws + OFF_DL);
    int*          cnt = (int*)  (ws + OFF_CNT);
    unsigned int* key = (unsigned int*)(ws + OFF_KEY);
    int*          sel = (int*)  (ws + OFF_SEL);
    float*        qg  = (float*)(ws + OFF_Q);
    float*        kg  = (float*)(ws + OFF_K);
    float*        vg  = (float*)(ws + OFF_V);
    float*        lp  = (float*)(ws + OFF_LP);
    float*        rl  = (float*)(ws + OFF_RL);
    float*        wg  = (float*)(ws + OFF_W);
    float*        pav = (float*)(ws + OFF_PAV);

    hipMemsetAsync(ws + OFF_CNT, 0, (size_t)NPTS * 4, stream);
    hipMemsetAsync(ws + OFF_W,   0, (size_t)NHEADS * KSEL * 4, stream);

    hipLaunchKernelGGL(k_center,   dim3(1),        dim3(64),   0, stream, lig, M, center);
    hipLaunchKernelGGL(k_prep,     dim3(64),       dim3(256),  0, stream, pos, center, px, py, pz, sq, dl);
    hipLaunchKernelGGL(k_neighbor, dim3(64, 8),    dim3(256),  0, stream, px, py, pz, sq, cnt);
    hipLaunchKernelGGL(k_scores,   dim3(64),       dim3(256),  0, stream, dl, cnt, key);
    hipLaunchKernelGGL(k_select,   dim3(1),        dim3(1024), 0, stream, key, sel);
    hipLaunchKernelGGL(k_qkv,      dim3(KSEL/16),  dim3(128),  0, stream, x, sel, Wn, bn, Wq, bq, Wk, bk, Wv, bv, qg, kg, vg);
    hipLaunchKernelGGL(k_attn_l,   dim3(16, 4, 8), dim3(256),  0, stream, qg, kg, lp);
    hipLaunchKernelGGL(k_combine,  dim3(128),      dim3(256),  0, stream, lp, rl);
    hipLaunchKernelGGL(k_attn_w,   dim3(16, 4, 8), dim3(256),  0, stream, qg, kg, rl, wg);
    hipLaunchKernelGGL(k_colsum,   dim3(128),      dim3(256),  0, stream, wg, vg, pav);
    hipLaunchKernelGGL(k_final,    dim3(1),        dim3(256),  0, stream, pav, Wo, bo, W1, b1, W2, b2, (float*)d_out);
}

// Round 2
// 450.340 us; speedup vs baseline: 1.0022x; 1.0022x over previous
//
#include <hip/hip_runtime.h>
#include <cstdint>
#include <cstddef>

#define NPTS 16384
#define KSEL 4096
#define HIDDEN 128
#define NHEADS 8
#define DHEAD 16
#define OUTD 256
#define NKSL 16   // k-slices for attn partials

// ---- workspace layout (bytes) ----
constexpr size_t OFF_PX  = 1024;
constexpr size_t OFF_PY  = OFF_PX  + (size_t)NPTS*4;
constexpr size_t OFF_PZ  = OFF_PY  + (size_t)NPTS*4;
constexpr size_t OFF_SQ  = OFF_PZ  + (size_t)NPTS*4;
constexpr size_t OFF_DL  = OFF_SQ  + (size_t)NPTS*4;
constexpr size_t OFF_CNT = OFF_DL  + (size_t)NPTS*4;      // int
constexpr size_t OFF_SEL = OFF_CNT + (size_t)NPTS*4;      // KSEL int
constexpr size_t OFF_Q   = OFF_SEL + (size_t)KSEL*4;      // KSEL*128 f32 (pre-scaled by log2e/4)
constexpr size_t OFF_K   = OFF_Q   + (size_t)KSEL*HIDDEN*4;
constexpr size_t OFF_V   = OFF_K   + (size_t)KSEL*HIDDEN*4;
constexpr size_t OFF_LP  = OFF_V   + (size_t)KSEL*HIDDEN*4;    // 8*4096*16 f32 partial l
constexpr size_t OFF_W   = OFF_LP  + (size_t)NHEADS*KSEL*NKSL*4; // 8*4096 f32 col weights
constexpr size_t OFF_PAV = OFF_W   + (size_t)NHEADS*KSEL*4;    // 128 f32 pooled av

__device__ __forceinline__ float dot16(const float4& a0, const float4& a1, const float4& a2, const float4& a3,
                                       const float4& b0, const float4& b1, const float4& b2, const float4& b3) {
    float p0 = fmaf(a0.x, b0.x, a0.y * b0.y); p0 = fmaf(a0.z, b0.z, p0); p0 = fmaf(a0.w, b0.w, p0);
    float p1 = fmaf(a1.x, b1.x, a1.y * b1.y); p1 = fmaf(a1.z, b1.z, p1); p1 = fmaf(a1.w, b1.w, p1);
    float p2 = fmaf(a2.x, b2.x, a2.y * b2.y); p2 = fmaf(a2.z, b2.z, p2); p2 = fmaf(a2.w, b2.w, p2);
    float p3 = fmaf(a3.x, b3.x, a3.y * b3.y); p3 = fmaf(a3.z, b3.z, p3); p3 = fmaf(a3.w, b3.w, p3);
    return (p0 + p1) + (p2 + p3);
}

// ---- 1. SoA pos + sq + d_lig (ligand center fused, computed per block) ----
__global__ void __launch_bounds__(256) k_prep(const float* __restrict__ pos, const float* __restrict__ lig, int M,
                       float* __restrict__ px, float* __restrict__ py, float* __restrict__ pz,
                       float* __restrict__ sq, float* __restrict__ dl) {
    __shared__ float ls[128];
    __shared__ float ctr[3];
    int tid = threadIdx.x;
    for (int i = tid; i < 3 * M; i += 256) ls[i] = lig[i];
    __syncthreads();
    if (tid < 3) {
        float s = 0.f;
        for (int i = 0; i < M; i++) s += ls[i * 3 + tid];
        ctr[tid] = s / (float)M;
    }
    __syncthreads();
    int i = blockIdx.x * 256 + tid;
    float x = pos[i*3+0], y = pos[i*3+1], z = pos[i*3+2];
    px[i] = x; py[i] = y; pz[i] = z;
    sq[i] = (x*x + y*y) + z*z;
    float dx = x - ctr[0], dy = y - ctr[1], dz = z - ctr[2];
    dl[i] = sqrtf((dx*dx + dy*dy) + dz*dz);
}

// ---- 2. neighbor counts (includes self; compensated in score) ----
__global__ void __launch_bounds__(256) k_neighbor(const float* __restrict__ px, const float* __restrict__ py,
                                                  const float* __restrict__ pz, const float* __restrict__ sq,
                                                  int* __restrict__ cnt) {
    __shared__ float4 xt[128], yt[128], zt[128], st[128];
    int tid = threadIdx.x;
    int i = blockIdx.x * 256 + tid;
    float xi = px[i], yi = py[i], zi = pz[i], si = sq[i];
    int jbase = blockIdx.y * 512;
    if (tid < 128) {
        xt[tid] = ((const float4*)(px + jbase))[tid];
        yt[tid] = ((const float4*)(py + jbase))[tid];
        zt[tid] = ((const float4*)(pz + jbase))[tid];
        st[tid] = ((const float4*)(sq + jbase))[tid];
    }
    __syncthreads();
    int c = 0;
    for (int t = 0; t < 128; t++) {
        float4 xj = xt[t], yj = yt[t], zj = zt[t], sj = st[t];
        { float dot = fmaf(xi, xj.x, fmaf(yi, yj.x, zi*zj.x)); float d2 = (si + sj.x) - 2.0f*dot; c += (d2 < 9.0f); }
        { float dot = fmaf(xi, xj.y, fmaf(yi, yj.y, zi*zj.y)); float d2 = (si + sj.y) - 2.0f*dot; c += (d2 < 9.0f); }
        { float dot = fmaf(xi, xj.z, fmaf(yi, yj.z, zi*zj.z)); float d2 = (si + sj.z) - 2.0f*dot; c += (d2 < 9.0f); }
        { float dot = fmaf(xi, xj.w, fmaf(yi, yj.w, zi*zj.w)); float d2 = (si + sj.w) - 2.0f*dot; c += (d2 < 9.0f); }
    }
    atomicAdd(&cnt[i], c);
}

// ---- 3. scores (fused) + exact top-KSEL radix select (ties -> lowest index) ----
__global__ void __launch_bounds__(1024) k_select(const float* __restrict__ dl, const int* __restrict__ cnt,
                                                 int* __restrict__ sel) {
    __shared__ unsigned int sk[NPTS];
    __shared__ int hist[256];
    __shared__ unsigned int s_prefix;
    __shared__ int s_rem, s_eqtot, s_nout, s_digit, s_cgt;
    int tid = threadIdx.x;
    for (int i = tid; i < NPTS; i += 1024) {
        float score = 1.0f / (1.0f + dl[i] / 5.0f) + 0.5f * (1.0f / (float)cnt[i]);
        unsigned int u = __float_as_uint(score);
        sk[i] = u ^ ((u & 0x80000000u) ? 0xFFFFFFFFu : 0x80000000u);
    }
    if (tid == 0) { s_prefix = 0; s_rem = KSEL; s_nout = 0; s_eqtot = 0; }
    __syncthreads();
    for (int p = 0; p < 4; p++) {
        int sh = 24 - 8 * p;
        if (tid < 256) hist[tid] = 0;
        __syncthreads();
        unsigned int pref = s_prefix;
        int shp = (p == 0) ? 0 : (32 - 8 * p);
        for (int i = tid; i < NPTS; i += 1024) {
            unsigned int key = sk[i];
            bool m = (p == 0) || ((key >> shp) == pref);
            if (m) atomicAdd(&hist[(key >> sh) & 255], 1);
        }
        __syncthreads();
        int rem = s_rem;
        if (tid < 256) {
            int cg = 0;
            for (int d = tid + 1; d < 256; d++) cg += hist[d];
            if (cg < rem && cg + hist[tid] >= rem) { s_digit = tid; s_cgt = cg; }
        }
        __syncthreads();
        if (tid == 0) {
            s_prefix = (s_prefix << 8) | (unsigned int)s_digit;
            s_rem = rem - s_cgt;
            if (p == 3) s_eqtot = hist[s_digit];
        }
        __syncthreads();
    }
    unsigned int T = s_prefix;
    int need_eq = s_rem;
    for (int i = tid; i < NPTS; i += 1024)
        if (sk[i] > T) sel[atomicAdd(&s_nout, 1)] = i;
    __syncthreads();
    if (s_eqtot == need_eq) {
        for (int i = tid; i < NPTS; i += 1024)
            if (sk[i] == T) sel[atomicAdd(&s_nout, 1)] = i;
    } else {
        for (int i = tid; i < NPTS; i += 1024) {
            if (sk[i] == T) {
                int rank = 0;
                for (int j = 0; j < i; j++) rank += (sk[j] == T);
                if (rank < need_eq) sel[atomicAdd(&s_nout, 1)] = i;
            }
        }
    }
}

// ---- 4. gather + node embed + QKV projections (8 rows/block) ----
__device__ __forceinline__ void proj8(const float hs[8][HIDDEN], const float* __restrict__ W,
                                      float b, int d, float* acc) {
    #pragma unroll
    for (int r = 0; r < 8; r++) acc[r] = b;
    for (int c = 0; c < HIDDEN; c += 4) {
        float w0 = W[(c+0)*HIDDEN+d], w1 = W[(c+1)*HIDDEN+d], w2 = W[(c+2)*HIDDEN+d], w3 = W[(c+3)*HIDDEN+d];
        #pragma unroll
        for (int r = 0; r < 8; r++) {
            float4 h4 = *(const float4*)&hs[r][c];
            float a = acc[r];
            a = fmaf(h4.x, w0, a); a = fmaf(h4.y, w1, a); a = fmaf(h4.z, w2, a); a = fmaf(h4.w, w3, a);
            acc[r] = a;
        }
    }
}

__global__ void __launch_bounds__(128) k_qkv(const float* __restrict__ x, const int* __restrict__ sel,
        const float* __restrict__ Wn, const float* __restrict__ bn,
        const float* __restrict__ Wq, const float* __restrict__ bq,
        const float* __restrict__ Wk, const float* __restrict__ bk,
        const float* __restrict__ Wv, const float* __restrict__ bv,
        float* __restrict__ qg, float* __restrict__ kg, float* __restrict__ vg) {
    __shared__ float xs[8][8];
    __shared__ __align__(16) float hs[8][HIDDEN];
    int d = threadIdx.x;
    int r0 = blockIdx.x * 8;
    if (d < 64) { int rr = d >> 3, cc = d & 7; xs[rr][cc] = x[(size_t)sel[r0 + rr] * 8 + cc]; }
    __syncthreads();
    {
        float wn[8];
        #pragma unroll
        for (int c = 0; c < 8; c++) wn[c] = Wn[c * HIDDEN + d];
        float b = bn[d];
        #pragma unroll
        for (int r = 0; r < 8; r++) {
            float a = b;
            #pragma unroll
            for (int c = 0; c < 8; c++) a = fmaf(xs[r][c], wn[c], a);
            hs[r][d] = a;
        }
    }
    __syncthreads();
    float acc[8];
    proj8(hs, Wq, bq[d], d, acc);
    #pragma unroll
    for (int r = 0; r < 8; r++) qg[(size_t)(r0+r)*HIDDEN + d] = acc[r] * 0.36067376022224085f; // log2(e)/4
    proj8(hs, Wk, bk[d], d, acc);
    #pragma unroll
    for (int r = 0; r < 8; r++) kg[(size_t)(r0+r)*HIDDEN + d] = acc[r];
    proj8(hs, Wv, bv[d], d, acc);
    #pragma unroll
    for (int r = 0; r < 8; r++) vg[(size_t)(r0+r)*HIDDEN + d] = acc[r];
}

// ---- 5. phase 1: l_q partials (2 q-rows/thread, 512 q-rows/block) ----
__global__ void __launch_bounds__(256) k_attn_l(const float* __restrict__ qg, const float* __restrict__ kg,
                                                float* __restrict__ lpart) {
    int ks = blockIdx.x, qt = blockIdx.y, h = blockIdx.z;
    int tid = threadIdx.x;
    __shared__ float4 kt[256][4];
    {
        const float4* src = (const float4*)(kg + ((size_t)(ks*256 + tid))*HIDDEN + h*DHEAD);
        kt[tid][0] = src[0]; kt[tid][1] = src[1]; kt[tid][2] = src[2]; kt[tid][3] = src[3];
    }
    int q0 = qt * 512 + tid * 2;
    float4 qa[2][4];
    #pragma unroll
    for (int r = 0; r < 2; r++) {
        const float4* qs = (const float4*)(qg + ((size_t)(q0+r))*HIDDEN + h*DHEAD);
        qa[r][0] = qs[0]; qa[r][1] = qs[1]; qa[r][2] = qs[2]; qa[r][3] = qs[3];
    }
    __syncthreads();
    float l0 = 0.f, l1 = 0.f;
    for (int j = 0; j < 256; j++) {
        float4 k0 = kt[j][0], k1 = kt[j][1], k2 = kt[j][2], k3 = kt[j][3];
        l0 += exp2f(dot16(qa[0][0], qa[0][1], qa[0][2], qa[0][3], k0, k1, k2, k3));
        l1 += exp2f(dot16(qa[1][0], qa[1][1], qa[1][2], qa[1][3], k0, k1, k2, k3));
    }
    size_t base = ((size_t)h * KSEL + q0) * NKSL + ks;
    lpart[base] = l0; lpart[base + NKSL] = l1;
}

// ---- 6. phase 2: column weights w_j = sum_q 2^(q'.k)/l_q  (1/l computed inline) ----
__global__ void __launch_bounds__(256) k_attn_w(const float* __restrict__ qg, const float* __restrict__ kg,
                                                const float* __restrict__ lpart, float* __restrict__ wg) {
    int qs = blockIdx.x, jt = blockIdx.y, h = blockIdx.z;
    int tid = threadIdx.x;
    __shared__ float4 qt4[256][4];
    __shared__ float rls[256];
    {
        const float4* src = (const float4*)(qg + ((size_t)(qs*256 + tid))*HIDDEN + h*DHEAD);
        qt4[tid][0] = src[0]; qt4[tid][1] = src[1]; qt4[tid][2] = src[2]; qt4[tid][3] = src[3];
        const float4* p = (const float4*)(lpart + ((size_t)h * KSEL + qs*256 + tid) * NKSL);
        float4 a = p[0], b = p[1], c = p[2], d = p[3];
        float s = ((a.x + a.y) + (a.z + a.w)) + ((b.x + b.y) + (b.z + b.w))
                + ((c.x + c.y) + (c.z + c.w)) + ((d.x + d.y) + (d.z + d.w));
        rls[tid] = 1.0f / s;
    }
    int j0 = jt * 512 + tid * 2;
    float4 kk[2][4];
    #pragma unroll
    for (int c = 0; c < 2; c++) {
        const float4* src = (const float4*)(kg + ((size_t)(j0+c))*HIDDEN + h*DHEAD);
        kk[c][0] = src[0]; kk[c][1] = src[1]; kk[c][2] = src[2]; kk[c][3] = src[3];
    }
    __syncthreads();
    float w0 = 0.f, w1 = 0.f;
    for (int q = 0; q < 256; q++) {
        float4 a0 = qt4[q][0], a1 = qt4[q][1], a2 = qt4[q][2], a3 = qt4[q][3];
        float r = rls[q];
        w0 = fmaf(exp2f(dot16(kk[0][0], kk[0][1], kk[0][2], kk[0][3], a0, a1, a2, a3)), r, w0);
        w1 = fmaf(exp2f(dot16(kk[1][0], kk[1][1], kk[1][2], kk[1][3], a0, a1, a2, a3)), r, w1);
    }
    size_t base = (size_t)h * KSEL + j0;
    atomicAdd(&wg[base+0], w0); atomicAdd(&wg[base+1], w1);
}

// ---- 7. pooled_av[d] += (1/K) sum_j w[h(d)][j] * v[j][d], coalesced over d ----
__global__ void __launch_bounds__(256) k_colsum(const float* __restrict__ wg, const float* __restrict__ vg,
                                                float* __restrict__ pav) {
    __shared__ float wl[NHEADS][128];
    __shared__ float red[128];
    int tid = threadIdx.x;
    int jb = blockIdx.x * 128;
    for (int i = tid; i < NHEADS * 128; i += 256) {
        int h = i >> 7, jl = i & 127;
        wl[h][jl] = wg[(size_t)h * KSEL + jb + jl];
    }
    __syncthreads();
    int d = tid & 127, g = tid >> 7;
    int h = d >> 4;
    float acc = 0.f;
    for (int jl = g * 64; jl < g * 64 + 64; jl++)
        acc = fmaf(wl[h][jl], vg[(size_t)(jb + jl) * HIDDEN + d], acc);
    if (g == 1) red[d] = acc;
    __syncthreads();
    if (g == 0) atomicAdd(&pav[d], (acc + red[d]) * (1.0f / (float)KSEL));
}

// ---- 8. out-proj + pool MLP ----
__global__ void __launch_bounds__(256) k_final(const float* __restrict__ pav,
        const float* __restrict__ Wo, const float* __restrict__ bo,
        const float* __restrict__ W1, const float* __restrict__ b1,
        const float* __restrict__ W2, const float* __restrict__ b2,
        float* __restrict__ out) {
    __shared__ float sp[HIDDEN];
    __shared__ float st[OUTD];
    int t = threadIdx.x;
    if (t < HIDDEN) {
        float a = bo[t];
        for (int c = 0; c < HIDDEN; c++) a = fmaf(pav[c], Wo[c * HIDDEN + t], a);
        sp[t] = a;
    }
    __syncthreads();
    {
        float a = b1[t];
        for (int c = 0; c < HIDDEN; c++) a = fmaf(sp[c], W1[c * OUTD + t], a);
        st[t] = fmaxf(a, 0.f);
    }
    __syncthreads();
    {
        float o = b2[t];
        for (int c = 0; c < OUTD; c++) o = fmaf(st[c], W2[c * OUTD + t], o);
        out[t] = o;
    }
}

extern "C" void kernel_launch(void* const* d_in, const int* in_sizes, int n_in,
                              void* d_out, int out_size, void* d_ws, size_t ws_size,
                              hipStream_t stream) {
    (void)n_in; (void)out_size; (void)ws_size;
    const float* x   = (const float*)d_in[0];
    const float* pos = (const float*)d_in[1];
    const float* lig = (const float*)d_in[2];
    const float* Wn  = (const float*)d_in[3];
    const float* bn  = (const float*)d_in[4];
    const float* Wq  = (const float*)d_in[5];
    const float* bq  = (const float*)d_in[6];
    const float* Wk  = (const float*)d_in[7];
    const float* bk  = (const float*)d_in[8];
    const float* Wv  = (const float*)d_in[9];
    const float* bv  = (const float*)d_in[10];
    const float* Wo  = (const float*)d_in[11];
    const float* bo  = (const float*)d_in[12];
    const float* W1  = (const float*)d_in[13];
    const float* b1  = (const float*)d_in[14];
    const float* W2  = (const float*)d_in[15];
    const float* b2  = (const float*)d_in[16];
    int M = in_sizes[2] / 3;

    char* ws = (char*)d_ws;
    float*        px  = (float*)(ws + OFF_PX);
    float*        py  = (float*)(ws + OFF_PY);
    float*        pz  = (float*)(ws + OFF_PZ);
    float*        sq  = (float*)(ws + OFF_SQ);
    float*        dl  = (float*)(ws + OFF_DL);
    int*          cnt = (int*)  (ws + OFF_CNT);
    int*          sel = (int*)  (ws + OFF_SEL);
    float*        qg  = (float*)(ws + OFF_Q);
    float*        kg  = (float*)(ws + OFF_K);
    float*        vg  = (float*)(ws + OFF_V);
    float*        lp  = (float*)(ws + OFF_LP);
    float*        wg  = (float*)(ws + OFF_W);
    float*        pav = (float*)(ws + OFF_PAV);

    hipMemsetAsync(ws + OFF_CNT, 0, (size_t)NPTS * 4, stream);
    hipMemsetAsync(ws + OFF_W,   0, (size_t)NHEADS * KSEL * 4, stream);
    hipMemsetAsync(ws + OFF_PAV, 0, (size_t)HIDDEN * 4, stream);

    hipLaunchKernelGGL(k_prep,     dim3(64),       dim3(256),  0, stream, pos, lig, M, px, py, pz, sq, dl);
    hipLaunchKernelGGL(k_neighbor, dim3(64, 32),   dim3(256),  0, stream, px, py, pz, sq, cnt);
    hipLaunchKernelGGL(k_select,   dim3(1),        dim3(1024), 0, stream, dl, cnt, sel);
    hipLaunchKernelGGL(k_qkv,      dim3(KSEL/8),   dim3(128),  0, stream, x, sel, Wn, bn, Wq, bq, Wk, bk, Wv, bv, qg, kg, vg);
    hipLaunchKernelGGL(k_attn_l,   dim3(16, 8, 8), dim3(256),  0, stream, qg, kg, lp);
    hipLaunchKernelGGL(k_attn_w,   dim3(16, 8, 8), dim3(256),  0, stream, qg, kg, lp, wg);
    hipLaunchKernelGGL(k_colsum,   dim3(32),       dim3(256),  0, stream, wg, vg, pav);
    hipLaunchKernelGGL(k_final,    dim3(1),        dim3(256),  0, stream, pav, Wo, bo, W1, b1, W2, b2, (float*)d_out);
}

// Round 3
// 387.939 us; speedup vs baseline: 1.1634x; 1.1609x over previous
//
#include <hip/hip_runtime.h>
#include <cstdint>
#include <cstddef>

#define NPTS 16384
#define KSEL 4096
#define HIDDEN 128
#define NHEADS 8
#define DHEAD 16
#define OUTD 256
#define NSLICE 8   // k/q slices for attn partials

typedef __attribute__((ext_vector_type(8))) short bf16x8;
typedef __attribute__((ext_vector_type(4))) float f32x4;

// ---- workspace layout (bytes) ----
constexpr size_t OFF_PX  = 1024;
constexpr size_t OFF_PY  = OFF_PX  + (size_t)NPTS*4;
constexpr size_t OFF_PZ  = OFF_PY  + (size_t)NPTS*4;
constexpr size_t OFF_SQ  = OFF_PZ  + (size_t)NPTS*4;
constexpr size_t OFF_DL  = OFF_SQ  + (size_t)NPTS*4;
constexpr size_t OFF_CNT = OFF_DL  + (size_t)NPTS*4;      // int
constexpr size_t OFF_SEL = OFF_CNT + (size_t)NPTS*4;      // KSEL int
constexpr size_t SZ_BF   = (size_t)NHEADS*KSEL*DHEAD*2;   // 1 MB per bf16 head-sliced array
constexpr size_t OFF_QH  = OFF_SEL + (size_t)KSEL*4;
constexpr size_t OFF_QL  = OFF_QH + SZ_BF;
constexpr size_t OFF_KH  = OFF_QL + SZ_BF;
constexpr size_t OFF_KL  = OFF_KH + SZ_BF;
constexpr size_t OFF_V   = OFF_KL + SZ_BF;                       // KSEL*128 f32
constexpr size_t OFF_LP  = OFF_V  + (size_t)KSEL*HIDDEN*4;       // 8*4096*8 f32 partial l
constexpr size_t OFF_WP  = OFF_LP + (size_t)NHEADS*KSEL*NSLICE*4; // 8*4096*8 f32 partial w
constexpr size_t OFF_PAV = OFF_WP + (size_t)NHEADS*KSEL*NSLICE*4; // 128 f32

__device__ __forceinline__ unsigned short f2bf(float f) {
    union { float f; unsigned u; } v; v.f = f;
    unsigned r = v.u + 0x7fffu + ((v.u >> 16) & 1u);
    return (unsigned short)(r >> 16);
}
__device__ __forceinline__ float bf2f(unsigned short h) {
    union { unsigned u; float f; } v; v.u = ((unsigned)h) << 16;
    return v.f;
}

// ---- 1. SoA pos + sq + d_lig (ligand center fused) ----
__global__ void __launch_bounds__(256) k_prep(const float* __restrict__ pos, const float* __restrict__ lig, int M,
                       float* __restrict__ px, float* __restrict__ py, float* __restrict__ pz,
                       float* __restrict__ sq, float* __restrict__ dl) {
    __shared__ float ls[128];
    __shared__ float ctr[3];
    int tid = threadIdx.x;
    for (int i = tid; i < 3 * M; i += 256) ls[i] = lig[i];
    __syncthreads();
    if (tid < 3) {
        float s = 0.f;
        for (int i = 0; i < M; i++) s += ls[i * 3 + tid];
        ctr[tid] = s / (float)M;
    }
    __syncthreads();
    int i = blockIdx.x * 256 + tid;
    float x = pos[i*3+0], y = pos[i*3+1], z = pos[i*3+2];
    px[i] = x; py[i] = y; pz[i] = z;
    sq[i] = (x*x + y*y) + z*z;
    float dx = x - ctr[0], dy = y - ctr[1], dz = z - ctr[2];
    dl[i] = sqrtf((dx*dx + dy*dy) + dz*dz);
}

// ---- 2. neighbor counts (includes self; compensated in score) ----
__global__ void __launch_bounds__(256) k_neighbor(const float* __restrict__ px, const float* __restrict__ py,
                                                  const float* __restrict__ pz, const float* __restrict__ sq,
                                                  int* __restrict__ cnt) {
    __shared__ float4 xt[128], yt[128], zt[128], st[128];
    int tid = threadIdx.x;
    int i = blockIdx.x * 256 + tid;
    float xi = px[i], yi = py[i], zi = pz[i], si = sq[i];
    int jbase = blockIdx.y * 512;
    if (tid < 128) {
        xt[tid] = ((const float4*)(px + jbase))[tid];
        yt[tid] = ((const float4*)(py + jbase))[tid];
        zt[tid] = ((const float4*)(pz + jbase))[tid];
        st[tid] = ((const float4*)(sq + jbase))[tid];
    }
    __syncthreads();
    int c = 0;
    for (int t = 0; t < 128; t++) {
        float4 xj = xt[t], yj = yt[t], zj = zt[t], sj = st[t];
        { float dot = fmaf(xi, xj.x, fmaf(yi, yj.x, zi*zj.x)); float d2 = (si + sj.x) - 2.0f*dot; c += (d2 < 9.0f); }
        { float dot = fmaf(xi, xj.y, fmaf(yi, yj.y, zi*zj.y)); float d2 = (si + sj.y) - 2.0f*dot; c += (d2 < 9.0f); }
        { float dot = fmaf(xi, xj.z, fmaf(yi, yj.z, zi*zj.z)); float d2 = (si + sj.z) - 2.0f*dot; c += (d2 < 9.0f); }
        { float dot = fmaf(xi, xj.w, fmaf(yi, yj.w, zi*zj.w)); float d2 = (si + sj.w) - 2.0f*dot; c += (d2 < 9.0f); }
    }
    atomicAdd(&cnt[i], c);
}

// ---- 3. scores (fused) + exact top-KSEL radix select (ties -> lowest index) ----
__global__ void __launch_bounds__(1024) k_select(const float* __restrict__ dl, const int* __restrict__ cnt,
                                                 int* __restrict__ sel) {
    __shared__ unsigned int sk[NPTS];
    __shared__ int hist[256];
    __shared__ unsigned int s_prefix;
    __shared__ int s_rem, s_eqtot, s_nout, s_digit, s_cgt;
    int tid = threadIdx.x;
    for (int i = tid; i < NPTS; i += 1024) {
        float score = 1.0f / (1.0f + dl[i] / 5.0f) + 0.5f * (1.0f / (float)cnt[i]);
        unsigned int u = __float_as_uint(score);
        sk[i] = u ^ ((u & 0x80000000u) ? 0xFFFFFFFFu : 0x80000000u);
    }
    if (tid == 0) { s_prefix = 0; s_rem = KSEL; s_nout = 0; s_eqtot = 0; }
    __syncthreads();
    for (int p = 0; p < 4; p++) {
        int sh = 24 - 8 * p;
        if (tid < 256) hist[tid] = 0;
        __syncthreads();
        unsigned int pref = s_prefix;
        int shp = (p == 0) ? 0 : (32 - 8 * p);
        for (int i = tid; i < NPTS; i += 1024) {
            unsigned int key = sk[i];
            bool m = (p == 0) || ((key >> shp) == pref);
            if (m) atomicAdd(&hist[(key >> sh) & 255], 1);
        }
        __syncthreads();
        int rem = s_rem;
        if (tid < 256) {
            int cg = 0;
            for (int d = tid + 1; d < 256; d++) cg += hist[d];
            if (cg < rem && cg + hist[tid] >= rem) { s_digit = tid; s_cgt = cg; }
        }
        __syncthreads();
        if (tid == 0) {
            s_prefix = (s_prefix << 8) | (unsigned int)s_digit;
            s_rem = rem - s_cgt;
            if (p == 3) s_eqtot = hist[s_digit];
        }
        __syncthreads();
    }
    unsigned int T = s_prefix;
    int need_eq = s_rem;
    for (int i = tid; i < NPTS; i += 1024)
        if (sk[i] > T) sel[atomicAdd(&s_nout, 1)] = i;
    __syncthreads();
    if (s_eqtot == need_eq) {
        for (int i = tid; i < NPTS; i += 1024)
            if (sk[i] == T) sel[atomicAdd(&s_nout, 1)] = i;
    } else {
        for (int i = tid; i < NPTS; i += 1024) {
            if (sk[i] == T) {
                int rank = 0;
                for (int j = 0; j < i; j++) rank += (sk[j] == T);
                if (rank < need_eq) sel[atomicAdd(&s_nout, 1)] = i;
            }
        }
    }
}

// ---- 4. gather + node embed + QKV projections; Q/K -> bf16 hi/lo split, head-sliced ----
__device__ __forceinline__ void proj8(const float hs[8][HIDDEN], const float* __restrict__ W,
                                      float b, int d, float* acc) {
    #pragma unroll
    for (int r = 0; r < 8; r++) acc[r] = b;
    for (int c = 0; c < HIDDEN; c += 4) {
        float w0 = W[(c+0)*HIDDEN+d], w1 = W[(c+1)*HIDDEN+d], w2 = W[(c+2)*HIDDEN+d], w3 = W[(c+3)*HIDDEN+d];
        #pragma unroll
        for (int r = 0; r < 8; r++) {
            float4 h4 = *(const float4*)&hs[r][c];
            float a = acc[r];
            a = fmaf(h4.x, w0, a); a = fmaf(h4.y, w1, a); a = fmaf(h4.z, w2, a); a = fmaf(h4.w, w3, a);
            acc[r] = a;
        }
    }
}

__global__ void __launch_bounds__(128) k_qkv(const float* __restrict__ x, const int* __restrict__ sel,
        const float* __restrict__ Wn, const float* __restrict__ bn,
        const float* __restrict__ Wq, const float* __restrict__ bq,
        const float* __restrict__ Wk, const float* __restrict__ bk,
        const float* __restrict__ Wv, const float* __restrict__ bv,
        unsigned short* __restrict__ qhg, unsigned short* __restrict__ qlg,
        unsigned short* __restrict__ khg, unsigned short* __restrict__ klg,
        float* __restrict__ vg) {
    __shared__ float xs[8][8];
    __shared__ __align__(16) float hs[8][HIDDEN];
    int d = threadIdx.x;
    int r0 = blockIdx.x * 8;
    if (d < 64) { int rr = d >> 3, cc = d & 7; xs[rr][cc] = x[(size_t)sel[r0 + rr] * 8 + cc]; }
    __syncthreads();
    {
        float wn[8];
        #pragma unroll
        for (int c = 0; c < 8; c++) wn[c] = Wn[c * HIDDEN + d];
        float b = bn[d];
        #pragma unroll
        for (int r = 0; r < 8; r++) {
            float a = b;
            #pragma unroll
            for (int c = 0; c < 8; c++) a = fmaf(xs[r][c], wn[c], a);
            hs[r][d] = a;
        }
    }
    __syncthreads();
    int hh = d >> 4, dd = d & 15;
    float acc[8];
    // Q (pre-scaled by log2(e)/4, then split)
    proj8(hs, Wq, bq[d], d, acc);
    #pragma unroll
    for (int r = 0; r < 8; r++) {
        float val = acc[r] * 0.36067376022224085f;
        unsigned short hi = f2bf(val);
        unsigned short lo = f2bf(val - bf2f(hi));
        size_t idx = ((size_t)(hh * KSEL) + r0 + r) * DHEAD + dd;
        qhg[idx] = hi; qlg[idx] = lo;
    }
    // K
    proj8(hs, Wk, bk[d], d, acc);
    #pragma unroll
    for (int r = 0; r < 8; r++) {
        float val = acc[r];
        unsigned short hi = f2bf(val);
        unsigned short lo = f2bf(val - bf2f(hi));
        size_t idx = ((size_t)(hh * KSEL) + r0 + r) * DHEAD + dd;
        khg[idx] = hi; klg[idx] = lo;
    }
    // V (fp32, row-major [q][128])
    proj8(hs, Wv, bv[d], d, acc);
    #pragma unroll
    for (int r = 0; r < 8; r++) vg[(size_t)(r0+r)*HIDDEN + d] = acc[r];
}

// ---- 5. phase 1: row sums l_q via MFMA; S = QhKh + QlKh + QhKl ----
// grid (kslice=8, qgroup=64, head=8), block 256 = 4 waves; wave = one 16-q tile x 512-k strip
__global__ void __launch_bounds__(256) k_attn_l(
        const unsigned short* __restrict__ qhg, const unsigned short* __restrict__ qlg,
        const unsigned short* __restrict__ khg, const unsigned short* __restrict__ klg,
        float* __restrict__ lp) {
    __shared__ short khs[512*24];  // rows padded to 24 bf16 (48B, 16B-aligned, conflict-free b128)
    __shared__ short kls[512*24];
    int tid = threadIdx.x;
    int ks_ = blockIdx.x, yg = blockIdx.y, h = blockIdx.z;
    size_t hb = (size_t)h * KSEL * DHEAD;
    int j0 = ks_ * 512;
    for (int r = tid; r < 512; r += 256) {
        const bf16x8* s1 = (const bf16x8*)(khg + hb + (size_t)(j0 + r) * DHEAD);
        *(bf16x8*)&khs[r*24]   = s1[0];
        *(bf16x8*)&khs[r*24+8] = s1[1];
        const bf16x8* s2 = (const bf16x8*)(klg + hb + (size_t)(j0 + r) * DHEAD);
        *(bf16x8*)&kls[r*24]   = s2[0];
        *(bf16x8*)&kls[r*24+8] = s2[1];
    }
    int lane = tid & 63, w = tid >> 6;
    int quad = lane >> 4, col = lane & 15;
    int q0w = yg * 64 + w * 16;
    // A = [Qh | Ql] along K=32: quads 0,1 -> Qh d0..15; quads 2,3 -> Ql d0..15
    const unsigned short* qsrc = (quad < 2 ? qhg : qlg) + hb + (size_t)(q0w + col) * DHEAD + (quad & 1) * 8;
    bf16x8 afrag = *(const bf16x8*)qsrc;
    __syncthreads();
    float l0 = 0.f, l1 = 0.f, l2 = 0.f, l3 = 0.f;
    int rowoff = col * 24 + (quad & 1) * 8;
    for (int t = 0; t < 32; t++) {
        bf16x8 b1 = *(const bf16x8*)&khs[t*384 + rowoff];          // B1 = [Kh | Kh]
        bf16x8 b2 = {0,0,0,0,0,0,0,0};                              // B2 = [Kl | 0]
        if (quad < 2) b2 = *(const bf16x8*)&kls[t*384 + rowoff];
        f32x4 c = {0.f, 0.f, 0.f, 0.f};
        c = __builtin_amdgcn_mfma_f32_16x16x32_bf16(afrag, b1, c, 0, 0, 0); // QhKh + QlKh
        c = __builtin_amdgcn_mfma_f32_16x16x32_bf16(afrag, b2, c, 0, 0, 0); // + QhKl
        l0 += exp2f(c[0]); l1 += exp2f(c[1]); l2 += exp2f(c[2]); l3 += exp2f(c[3]);
    }
    #pragma unroll
    for (int m = 1; m < 16; m <<= 1) {
        l0 += __shfl_xor(l0, m); l1 += __shfl_xor(l1, m);
        l2 += __shfl_xor(l2, m); l3 += __shfl_xor(l3, m);
    }
    if (col == 0) {
        size_t base = ((size_t)(h * KSEL) + q0w + quad * 4) * NSLICE + ks_;
        lp[base]      = l0; lp[base + NSLICE]   = l1;
        lp[base + 2*NSLICE] = l2; lp[base + 3*NSLICE] = l3;
    }
}

// ---- 6. phase 2: column weights w_j = sum_q exp(s)/l_q via MFMA (A = K-tile [Kh|Kl]) ----
// grid (qslice=8, jgroup=64, head=8)
__global__ void __launch_bounds__(256) k_attn_w(
        const unsigned short* __restrict__ qhg, const unsigned short* __restrict__ qlg,
        const unsigned short* __restrict__ khg, const unsigned short* __restrict__ klg,
        const float* __restrict__ lp, float* __restrict__ wp) {
    __shared__ short qhs[512*24];
    __shared__ short qls[512*24];
    __shared__ float rls[512];
    int tid = threadIdx.x;
    int qs_ = blockIdx.x, yg = blockIdx.y, h = blockIdx.z;
    size_t hb = (size_t)h * KSEL * DHEAD;
    int qbase = qs_ * 512;
    for (int r = tid; r < 512; r += 256) {
        const bf16x8* s1 = (const bf16x8*)(qhg + hb + (size_t)(qbase + r) * DHEAD);
        *(bf16x8*)&qhs[r*24]   = s1[0];
        *(bf16x8*)&qhs[r*24+8] = s1[1];
        const bf16x8* s2 = (const bf16x8*)(qlg + hb + (size_t)(qbase + r) * DHEAD);
        *(bf16x8*)&qls[r*24]   = s2[0];
        *(bf16x8*)&qls[r*24+8] = s2[1];
        const float4* p = (const float4*)&lp[((size_t)(h * KSEL) + qbase + r) * NSLICE];
        float4 a = p[0], b = p[1];
        float s = ((a.x + a.y) + (a.z + a.w)) + ((b.x + b.y) + (b.z + b.w));
        rls[r] = 1.0f / s;
    }
    int lane = tid & 63, w = tid >> 6;
    int quad = lane >> 4, col = lane & 15;
    int j0w = yg * 64 + w * 16;
    // A = [Kh | Kl]: quads 0,1 -> Kh; quads 2,3 -> Kl
    const unsigned short* ksrc = (quad < 2 ? khg : klg) + hb + (size_t)(j0w + col) * DHEAD + (quad & 1) * 8;
    bf16x8 afrag = *(const bf16x8*)ksrc;
    __syncthreads();
    float w0 = 0.f, w1 = 0.f, w2 = 0.f, w3 = 0.f;
    int rowoff = col * 24 + (quad & 1) * 8;
    for (int t = 0; t < 32; t++) {
        bf16x8 b1 = *(const bf16x8*)&qhs[t*384 + rowoff];          // B1 = [Qh | Qh]
        bf16x8 b2 = {0,0,0,0,0,0,0,0};                              // B2 = [Ql | 0]
        if (quad < 2) b2 = *(const bf16x8*)&qls[t*384 + rowoff];
        f32x4 c = {0.f, 0.f, 0.f, 0.f};
        c = __builtin_amdgcn_mfma_f32_16x16x32_bf16(afrag, b1, c, 0, 0, 0); // KhQh + KlQh
        c = __builtin_amdgcn_mfma_f32_16x16x32_bf16(afrag, b2, c, 0, 0, 0); // + KhQl
        float rlv = rls[t * 16 + col];  // col = q-local
        w0 = fmaf(exp2f(c[0]), rlv, w0); w1 = fmaf(exp2f(c[1]), rlv, w1);
        w2 = fmaf(exp2f(c[2]), rlv, w2); w3 = fmaf(exp2f(c[3]), rlv, w3);
    }
    #pragma unroll
    for (int m = 1; m < 16; m <<= 1) {
        w0 += __shfl_xor(w0, m); w1 += __shfl_xor(w1, m);
        w2 += __shfl_xor(w2, m); w3 += __shfl_xor(w3, m);
    }
    if (col == 0) {
        size_t base = ((size_t)(h * KSEL) + j0w + quad * 4) * NSLICE + qs_;
        wp[base]      = w0; wp[base + NSLICE]   = w1;
        wp[base + 2*NSLICE] = w2; wp[base + 3*NSLICE] = w3;
    }
}

// ---- 7. pooled_av[d] += (1/K) sum_j w[h(d)][j] * v[j][d] ----
__global__ void __launch_bounds__(256) k_colsum(const float* __restrict__ wp, const float* __restrict__ vg,
                                                float* __restrict__ pav) {
    __shared__ float wl[NHEADS][128];
    __shared__ float red[128];
    int tid = threadIdx.x;
    int jb = blockIdx.x * 128;
    for (int i = tid; i < NHEADS * 128; i += 256) {
        int h = i >> 7, jl = i & 127;
        const float4* p = (const float4*)&wp[((size_t)(h * KSEL) + jb + jl) * NSLICE];
        float4 a = p[0], b = p[1];
        wl[h][jl] = ((a.x + a.y) + (a.z + a.w)) + ((b.x + b.y) + (b.z + b.w));
    }
    __syncthreads();
    int d = tid & 127, g = tid >> 7;
    int h = d >> 4;
    float acc = 0.f;
    for (int jl = g * 64; jl < g * 64 + 64; jl++)
        acc = fmaf(wl[h][jl], vg[(size_t)(jb + jl) * HIDDEN + d], acc);
    if (g == 1) red[d] = acc;
    __syncthreads();
    if (g == 0) atomicAdd(&pav[d], (acc + red[d]) * (1.0f / (float)KSEL));
}

// ---- 8. out-proj + pool MLP ----
__global__ void __launch_bounds__(256) k_final(const float* __restrict__ pav,
        const float* __restrict__ Wo, const float* __restrict__ bo,
        const float* __restrict__ W1, const float* __restrict__ b1,
        const float* __restrict__ W2, const float* __restrict__ b2,
        float* __restrict__ out) {
    __shared__ float sp[HIDDEN];
    __shared__ float st[OUTD];
    int t = threadIdx.x;
    if (t < HIDDEN) {
        float a = bo[t];
        for (int c = 0; c < HIDDEN; c++) a = fmaf(pav[c], Wo[c * HIDDEN + t], a);
        sp[t] = a;
    }
    __syncthreads();
    {
        float a = b1[t];
        for (int c = 0; c < HIDDEN; c++) a = fmaf(sp[c], W1[c * OUTD + t], a);
        st[t] = fmaxf(a, 0.f);
    }
    __syncthreads();
    {
        float o = b2[t];
        for (int c = 0; c < OUTD; c++) o = fmaf(st[c], W2[c * OUTD + t], o);
        out[t] = o;
    }
}

extern "C" void kernel_launch(void* const* d_in, const int* in_sizes, int n_in,
                              void* d_out, int out_size, void* d_ws, size_t ws_size,
                              hipStream_t stream) {
    (void)n_in; (void)out_size; (void)ws_size;
    const float* x   = (const float*)d_in[0];
    const float* pos = (const float*)d_in[1];
    const float* lig = (const float*)d_in[2];
    const float* Wn  = (const float*)d_in[3];
    const float* bn  = (const float*)d_in[4];
    const float* Wq  = (const float*)d_in[5];
    const float* bq  = (const float*)d_in[6];
    const float* Wk  = (const float*)d_in[7];
    const float* bk  = (const float*)d_in[8];
    const float* Wv  = (const float*)d_in[9];
    const float* bv  = (const float*)d_in[10];
    const float* Wo  = (const float*)d_in[11];
    const float* bo  = (const float*)d_in[12];
    const float* W1  = (const float*)d_in[13];
    const float* b1  = (const float*)d_in[14];
    const float* W2  = (const float*)d_in[15];
    const float* b2  = (const float*)d_in[16];
    int M = in_sizes[2] / 3;

    char* ws = (char*)d_ws;
    float*          px  = (float*)(ws + OFF_PX);
    float*          py  = (float*)(ws + OFF_PY);
    float*          pz  = (float*)(ws + OFF_PZ);
    float*          sq  = (float*)(ws + OFF_SQ);
    float*          dl  = (float*)(ws + OFF_DL);
    int*            cnt = (int*)  (ws + OFF_CNT);
    int*            sel = (int*)  (ws + OFF_SEL);
    unsigned short* qhg = (unsigned short*)(ws + OFF_QH);
    unsigned short* qlg = (unsigned short*)(ws + OFF_QL);
    unsigned short* khg = (unsigned short*)(ws + OFF_KH);
    unsigned short* klg = (unsigned short*)(ws + OFF_KL);
    float*          vg  = (float*)(ws + OFF_V);
    float*          lp  = (float*)(ws + OFF_LP);
    float*          wp  = (float*)(ws + OFF_WP);
    float*          pav = (float*)(ws + OFF_PAV);

    hipMemsetAsync(ws + OFF_CNT, 0, (size_t)NPTS * 4, stream);
    hipMemsetAsync(ws + OFF_PAV, 0, (size_t)HIDDEN * 4, stream);

    hipLaunchKernelGGL(k_prep,     dim3(64),       dim3(256),  0, stream, pos, lig, M, px, py, pz, sq, dl);
    hipLaunchKernelGGL(k_neighbor, dim3(64, 32),   dim3(256),  0, stream, px, py, pz, sq, cnt);
    hipLaunchKernelGGL(k_select,   dim3(1),        dim3(1024), 0, stream, dl, cnt, sel);
    hipLaunchKernelGGL(k_qkv,      dim3(KSEL/8),   dim3(128),  0, stream, x, sel, Wn, bn, Wq, bq, Wk, bk, Wv, bv, qhg, qlg, khg, klg, vg);
    hipLaunchKernelGGL(k_attn_l,   dim3(8, 64, 8), dim3(256),  0, stream, qhg, qlg, khg, klg, lp);
    hipLaunchKernelGGL(k_attn_w,   dim3(8, 64, 8), dim3(256),  0, stream, qhg, qlg, khg, klg, lp, wp);
    hipLaunchKernelGGL(k_colsum,   dim3(32),       dim3(256),  0, stream, wp, vg, pav);
    hipLaunchKernelGGL(k_final,    dim3(1),        dim3(256),  0, stream, pav, Wo, bo, W1, b1, W2, b2, (float*)d_out);
}

// Round 4
// 289.692 us; speedup vs baseline: 1.5580x; 1.3391x over previous
//
#include <hip/hip_runtime.h>
#include <cstdint>
#include <cstddef>

#define NPTS 16384
#define KSEL 4096
#define HIDDEN 128
#define NHEADS 8
#define DHEAD 16
#define OUTD 256
#define NSLICE 4   // k/q slices for attn partials

typedef __attribute__((ext_vector_type(8))) short bf16x8;
typedef __attribute__((ext_vector_type(4))) float f32x4;

#if defined(__has_builtin)
#if __has_builtin(__builtin_amdgcn_exp2f)
#define E2(x) __builtin_amdgcn_exp2f(x)
#endif
#endif
#ifndef E2
#define E2(x) exp2f(x)
#endif

// ---- workspace layout (bytes) ----
constexpr size_t OFF_PX  = 1024;
constexpr size_t OFF_PY  = OFF_PX  + (size_t)NPTS*4;
constexpr size_t OFF_PZ  = OFF_PY  + (size_t)NPTS*4;
constexpr size_t OFF_SQ  = OFF_PZ  + (size_t)NPTS*4;
constexpr size_t OFF_DL  = OFF_SQ  + (size_t)NPTS*4;
constexpr size_t OFF_CNT = OFF_DL  + (size_t)NPTS*4;      // int
constexpr size_t OFF_SEL = OFF_CNT + (size_t)NPTS*4;      // KSEL int
constexpr size_t SZ_PK   = (size_t)NHEADS*KSEL*32*2;      // 2 MB packed [hi16|lo16] bf16
constexpr size_t OFF_QPK = OFF_SEL + (size_t)KSEL*4;
constexpr size_t OFF_KPK = OFF_QPK + SZ_PK;
constexpr size_t OFF_V   = OFF_KPK + SZ_PK;                      // KSEL*128 f32
constexpr size_t OFF_LP  = OFF_V  + (size_t)KSEL*HIDDEN*4;       // 8*4096*4 f32 partial l
constexpr size_t OFF_RL  = OFF_LP + (size_t)NHEADS*KSEL*NSLICE*4; // 8*4096 f32 1/l
constexpr size_t OFF_WP  = OFF_RL + (size_t)NHEADS*KSEL*4;        // 8*4096*4 f32 partial w
constexpr size_t OFF_PAV = OFF_WP + (size_t)NHEADS*KSEL*NSLICE*4; // 128 f32

__device__ __forceinline__ unsigned short f2bf(float f) {
    union { float f; unsigned u; } v; v.f = f;
    unsigned r = v.u + 0x7fffu + ((v.u >> 16) & 1u);
    return (unsigned short)(r >> 16);
}
__device__ __forceinline__ float bf2f(unsigned short h) {
    union { unsigned u; float f; } v; v.u = ((unsigned)h) << 16;
    return v.f;
}

// ---- 1. SoA pos + sq + d_lig (ligand center fused) ----
__global__ void __launch_bounds__(256) k_prep(const float* __restrict__ pos, const float* __restrict__ lig, int M,
                       float* __restrict__ px, float* __restrict__ py, float* __restrict__ pz,
                       float* __restrict__ sq, float* __restrict__ dl) {
    __shared__ float ls[128];
    __shared__ float ctr[3];
    int tid = threadIdx.x;
    for (int i = tid; i < 3 * M; i += 256) ls[i] = lig[i];
    __syncthreads();
    if (tid < 3) {
        float s = 0.f;
        for (int i = 0; i < M; i++) s += ls[i * 3 + tid];
        ctr[tid] = s / (float)M;
    }
    __syncthreads();
    int i = blockIdx.x * 256 + tid;
    float x = pos[i*3+0], y = pos[i*3+1], z = pos[i*3+2];
    px[i] = x; py[i] = y; pz[i] = z;
    sq[i] = (x*x + y*y) + z*z;
    float dx = x - ctr[0], dy = y - ctr[1], dz = z - ctr[2];
    dl[i] = sqrtf((dx*dx + dy*dy) + dz*dz);
}

// ---- 2. neighbor counts (includes self; compensated in score) ----
__global__ void __launch_bounds__(256) k_neighbor(const float* __restrict__ px, const float* __restrict__ py,
                                                  const float* __restrict__ pz, const float* __restrict__ sq,
                                                  int* __restrict__ cnt) {
    __shared__ float4 xt[128], yt[128], zt[128], st[128];
    int tid = threadIdx.x;
    int i = blockIdx.x * 256 + tid;
    float xi = px[i], yi = py[i], zi = pz[i], si = sq[i];
    int jbase = blockIdx.y * 512;
    if (tid < 128) {
        xt[tid] = ((const float4*)(px + jbase))[tid];
        yt[tid] = ((const float4*)(py + jbase))[tid];
        zt[tid] = ((const float4*)(pz + jbase))[tid];
        st[tid] = ((const float4*)(sq + jbase))[tid];
    }
    __syncthreads();
    int c = 0;
    for (int t = 0; t < 128; t++) {
        float4 xj = xt[t], yj = yt[t], zj = zt[t], sj = st[t];
        { float dot = fmaf(xi, xj.x, fmaf(yi, yj.x, zi*zj.x)); float d2 = (si + sj.x) - 2.0f*dot; c += (d2 < 9.0f); }
        { float dot = fmaf(xi, xj.y, fmaf(yi, yj.y, zi*zj.y)); float d2 = (si + sj.y) - 2.0f*dot; c += (d2 < 9.0f); }
        { float dot = fmaf(xi, xj.z, fmaf(yi, yj.z, zi*zj.z)); float d2 = (si + sj.z) - 2.0f*dot; c += (d2 < 9.0f); }
        { float dot = fmaf(xi, xj.w, fmaf(yi, yj.w, zi*zj.w)); float d2 = (si + sj.w) - 2.0f*dot; c += (d2 < 9.0f); }
    }
    atomicAdd(&cnt[i], c);
}

// ---- 3. scores (fused) + exact top-KSEL radix select (ties -> lowest index) ----
__global__ void __launch_bounds__(1024) k_select(const float* __restrict__ dl, const int* __restrict__ cnt,
                                                 int* __restrict__ sel) {
    __shared__ unsigned int sk[NPTS];
    __shared__ int hist[256];
    __shared__ unsigned int s_prefix;
    __shared__ int s_rem, s_eqtot, s_nout, s_digit, s_cgt;
    int tid = threadIdx.x;
    for (int i = tid; i < NPTS; i += 1024) {
        float score = 1.0f / (1.0f + dl[i] / 5.0f) + 0.5f * (1.0f / (float)cnt[i]);
        unsigned int u = __float_as_uint(score);
        sk[i] = u ^ ((u & 0x80000000u) ? 0xFFFFFFFFu : 0x80000000u);
    }
    if (tid == 0) { s_prefix = 0; s_rem = KSEL; s_nout = 0; s_eqtot = 0; }
    __syncthreads();
    for (int p = 0; p < 4; p++) {
        int sh = 24 - 8 * p;
        if (tid < 256) hist[tid] = 0;
        __syncthreads();
        unsigned int pref = s_prefix;
        int shp = (p == 0) ? 0 : (32 - 8 * p);
        for (int i = tid; i < NPTS; i += 1024) {
            unsigned int key = sk[i];
            bool m = (p == 0) || ((key >> shp) == pref);
            if (m) atomicAdd(&hist[(key >> sh) & 255], 1);
        }
        __syncthreads();
        int rem = s_rem;
        if (tid < 256) {
            int cg = 0;
            for (int d = tid + 1; d < 256; d++) cg += hist[d];
            if (cg < rem && cg + hist[tid] >= rem) { s_digit = tid; s_cgt = cg; }
        }
        __syncthreads();
        if (tid == 0) {
            s_prefix = (s_prefix << 8) | (unsigned int)s_digit;
            s_rem = rem - s_cgt;
            if (p == 3) s_eqtot = hist[s_digit];
        }
        __syncthreads();
    }
    unsigned int T = s_prefix;
    int need_eq = s_rem;
    for (int i = tid; i < NPTS; i += 1024)
        if (sk[i] > T) sel[atomicAdd(&s_nout, 1)] = i;
    __syncthreads();
    if (s_eqtot == need_eq) {
        for (int i = tid; i < NPTS; i += 1024)
            if (sk[i] == T) sel[atomicAdd(&s_nout, 1)] = i;
    } else {
        for (int i = tid; i < NPTS; i += 1024) {
            if (sk[i] == T) {
                int rank = 0;
                for (int j = 0; j < i; j++) rank += (sk[j] == T);
                if (rank < need_eq) sel[atomicAdd(&s_nout, 1)] = i;
            }
        }
    }
}

// ---- 4. gather + node embed + QKV projections; Q/K -> packed bf16 [hi16|lo16] rows ----
__device__ __forceinline__ void proj8(const float hs[8][HIDDEN], const float* __restrict__ W,
                                      float b, int d, float* acc) {
    #pragma unroll
    for (int r = 0; r < 8; r++) acc[r] = b;
    for (int c = 0; c < HIDDEN; c += 4) {
        float w0 = W[(c+0)*HIDDEN+d], w1 = W[(c+1)*HIDDEN+d], w2 = W[(c+2)*HIDDEN+d], w3 = W[(c+3)*HIDDEN+d];
        #pragma unroll
        for (int r = 0; r < 8; r++) {
            float4 h4 = *(const float4*)&hs[r][c];
            float a = acc[r];
            a = fmaf(h4.x, w0, a); a = fmaf(h4.y, w1, a); a = fmaf(h4.z, w2, a); a = fmaf(h4.w, w3, a);
            acc[r] = a;
        }
    }
}

__global__ void __launch_bounds__(128) k_qkv(const float* __restrict__ x, const int* __restrict__ sel,
        const float* __restrict__ Wn, const float* __restrict__ bn,
        const float* __restrict__ Wq, const float* __restrict__ bq,
        const float* __restrict__ Wk, const float* __restrict__ bk,
        const float* __restrict__ Wv, const float* __restrict__ bv,
        unsigned short* __restrict__ qpk, unsigned short* __restrict__ kpk,
        float* __restrict__ vg) {
    __shared__ float xs[8][8];
    __shared__ __align__(16) float hs[8][HIDDEN];
    int d = threadIdx.x;
    int r0 = blockIdx.x * 8;
    if (d < 64) { int rr = d >> 3, cc = d & 7; xs[rr][cc] = x[(size_t)sel[r0 + rr] * 8 + cc]; }
    __syncthreads();
    {
        float wn[8];
        #pragma unroll
        for (int c = 0; c < 8; c++) wn[c] = Wn[c * HIDDEN + d];
        float b = bn[d];
        #pragma unroll
        for (int r = 0; r < 8; r++) {
            float a = b;
            #pragma unroll
            for (int c = 0; c < 8; c++) a = fmaf(xs[r][c], wn[c], a);
            hs[r][d] = a;
        }
    }
    __syncthreads();
    int hh = d >> 4, dd = d & 15;
    float acc[8];
    // Q (pre-scaled by log2(e)/4, split hi/lo)
    proj8(hs, Wq, bq[d], d, acc);
    #pragma unroll
    for (int r = 0; r < 8; r++) {
        float val = acc[r] * 0.36067376022224085f;
        unsigned short hi = f2bf(val);
        unsigned short lo = f2bf(val - bf2f(hi));
        size_t idx = ((size_t)(hh * KSEL) + r0 + r) * 32 + dd;
        qpk[idx] = hi; qpk[idx + 16] = lo;
    }
    // K
    proj8(hs, Wk, bk[d], d, acc);
    #pragma unroll
    for (int r = 0; r < 8; r++) {
        float val = acc[r];
        unsigned short hi = f2bf(val);
        unsigned short lo = f2bf(val - bf2f(hi));
        size_t idx = ((size_t)(hh * KSEL) + r0 + r) * 32 + dd;
        kpk[idx] = hi; kpk[idx + 16] = lo;
    }
    // V (fp32, row-major [q][128])
    proj8(hs, Wv, bv[d], d, acc);
    #pragma unroll
    for (int r = 0; r < 8; r++) vg[(size_t)(r0+r)*HIDDEN + d] = acc[r];
}

// ---- 5. phase 1: row sums l_q via MFMA; chunked LDS (256 rows, 80B stride) ----
// grid (kslice=4, qgroup=64, head=8), block 256 = 4 waves; wave = 16-q tile x 1024-k strip
__global__ void __launch_bounds__(256) k_attn_l(
        const unsigned short* __restrict__ qpk, const unsigned short* __restrict__ kpk,
        float* __restrict__ lp) {
    __shared__ unsigned short smem[256 * 40];  // 80B row stride: conflict-free b128 groups
    int tid = threadIdx.x;
    int ks = blockIdx.x, yg = blockIdx.y, h = blockIdx.z;
    size_t hb = (size_t)h * KSEL;
    int lane = tid & 63, w = tid >> 6;
    int n = lane & 15, g = lane >> 4;
    int q0w = yg * 64 + w * 16;
    bf16x8 afrag = *(const bf16x8*)(qpk + (hb + q0w + n) * 32 + g * 8); // A=[Qh|Ql]
    float l0 = 0.f, l1 = 0.f, l2 = 0.f, l3 = 0.f;
    int b1off = (g & 1) * 8;
    int b2off = 16 + g * 8;
    for (int kc = 0; kc < 4; kc++) {
        __syncthreads();
        {
            int krow = ks * 1024 + kc * 256 + tid;
            const float4* src = (const float4*)(kpk + (hb + krow) * 32);
            float4 a0 = src[0], a1 = src[1], a2 = src[2], a3 = src[3];
            float4* dst = (float4*)&smem[tid * 40];
            dst[0] = a0; dst[1] = a1; dst[2] = a2; dst[3] = a3;
        }
        __syncthreads();
        #pragma unroll 4
        for (int t = 0; t < 16; t++) {
            const unsigned short* rowp = &smem[(t * 16 + n) * 40];
            bf16x8 b1 = *(const bf16x8*)(rowp + b1off);            // [Kh|Kh]
            bf16x8 b2 = {0,0,0,0,0,0,0,0};                          // [Kl|0]
            if (g < 2) b2 = *(const bf16x8*)(rowp + b2off);
            f32x4 c = {0.f, 0.f, 0.f, 0.f};
            c = __builtin_amdgcn_mfma_f32_16x16x32_bf16(afrag, b1, c, 0, 0, 0);
            c = __builtin_amdgcn_mfma_f32_16x16x32_bf16(afrag, b2, c, 0, 0, 0);
            l0 += E2(c[0]); l1 += E2(c[1]); l2 += E2(c[2]); l3 += E2(c[3]);
        }
    }
    #pragma unroll
    for (int m = 1; m < 16; m <<= 1) {
        l0 += __shfl_xor(l0, m); l1 += __shfl_xor(l1, m);
        l2 += __shfl_xor(l2, m); l3 += __shfl_xor(l3, m);
    }
    if (n == 0) {
        size_t base = (hb + q0w + g * 4) * NSLICE + ks;
        lp[base]            = l0; lp[base + NSLICE]     = l1;
        lp[base + 2*NSLICE] = l2; lp[base + 3*NSLICE]   = l3;
    }
}

// ---- 6. combine l partials -> 1/l ----
__global__ void k_rl(const float* __restrict__ lp, float* __restrict__ rl) {
    int i = blockIdx.x * 256 + threadIdx.x;
    float4 p = ((const float4*)lp)[i];
    rl[i] = 1.0f / ((p.x + p.y) + (p.z + p.w));
}

// ---- 7. phase 2: column weights w_j = sum_q exp(s)/l_q (A = K-row [Kh|Kl]) ----
__global__ void __launch_bounds__(256) k_attn_w(
        const unsigned short* __restrict__ qpk, const unsigned short* __restrict__ kpk,
        const float* __restrict__ rl, float* __restrict__ wp) {
    __shared__ unsigned short smem[256 * 40];
    __shared__ float rls[256];
    int tid = threadIdx.x;
    int qs = blockIdx.x, yg = blockIdx.y, h = blockIdx.z;
    size_t hb = (size_t)h * KSEL;
    int lane = tid & 63, w = tid >> 6;
    int n = lane & 15, g = lane >> 4;
    int j0w = yg * 64 + w * 16;
    bf16x8 afrag = *(const bf16x8*)(kpk + (hb + j0w + n) * 32 + g * 8); // A=[Kh|Kl]
    float w0 = 0.f, w1 = 0.f, w2 = 0.f, w3 = 0.f;
    int b1off = (g & 1) * 8;
    int b2off = 16 + g * 8;
    for (int qc = 0; qc < 4; qc++) {
        __syncthreads();
        {
            int qrow = qs * 1024 + qc * 256 + tid;
            const float4* src = (const float4*)(qpk + (hb + qrow) * 32);
            float4 a0 = src[0], a1 = src[1], a2 = src[2], a3 = src[3];
            float4* dst = (float4*)&smem[tid * 40];
            dst[0] = a0; dst[1] = a1; dst[2] = a2; dst[3] = a3;
            rls[tid] = rl[hb + qrow];
        }
        __syncthreads();
        #pragma unroll 4
        for (int t = 0; t < 16; t++) {
            const unsigned short* rowp = &smem[(t * 16 + n) * 40];
            bf16x8 b1 = *(const bf16x8*)(rowp + b1off);            // [Qh|Qh]
            bf16x8 b2 = {0,0,0,0,0,0,0,0};                          // [Ql|0]
            if (g < 2) b2 = *(const bf16x8*)(rowp + b2off);
            f32x4 c = {0.f, 0.f, 0.f, 0.f};
            c = __builtin_amdgcn_mfma_f32_16x16x32_bf16(afrag, b1, c, 0, 0, 0);
            c = __builtin_amdgcn_mfma_f32_16x16x32_bf16(afrag, b2, c, 0, 0, 0);
            float rv = rls[t * 16 + n];
            w0 = fmaf(E2(c[0]), rv, w0); w1 = fmaf(E2(c[1]), rv, w1);
            w2 = fmaf(E2(c[2]), rv, w2); w3 = fmaf(E2(c[3]), rv, w3);
        }
    }
    #pragma unroll
    for (int m = 1; m < 16; m <<= 1) {
        w0 += __shfl_xor(w0, m); w1 += __shfl_xor(w1, m);
        w2 += __shfl_xor(w2, m); w3 += __shfl_xor(w3, m);
    }
    if (n == 0) {
        size_t base = (hb + j0w + g * 4) * NSLICE + qs;
        wp[base]            = w0; wp[base + NSLICE]     = w1;
        wp[base + 2*NSLICE] = w2; wp[base + 3*NSLICE]   = w3;
    }
}

// ---- 8. pooled_av[d] += (1/K) sum_j w[h(d)][j] * v[j][d] ----
__global__ void __launch_bounds__(256) k_colsum(const float* __restrict__ wp, const float* __restrict__ vg,
                                                float* __restrict__ pav) {
    __shared__ float wl[NHEADS][128];
    __shared__ float red[128];
    int tid = threadIdx.x;
    int jb = blockIdx.x * 128;
    for (int i = tid; i < NHEADS * 128; i += 256) {
        int h = i >> 7, jl = i & 127;
        float4 p = ((const float4*)wp)[(size_t)h * KSEL + jb + jl];
        wl[h][jl] = (p.x + p.y) + (p.z + p.w);
    }
    __syncthreads();
    int d = tid & 127, g = tid >> 7;
    int h = d >> 4;
    float acc = 0.f;
    for (int jl = g * 64; jl < g * 64 + 64; jl++)
        acc = fmaf(wl[h][jl], vg[(size_t)(jb + jl) * HIDDEN + d], acc);
    if (g == 1) red[d] = acc;
    __syncthreads();
    if (g == 0) atomicAdd(&pav[d], (acc + red[d]) * (1.0f / (float)KSEL));
}

// ---- 9. out-proj + pool MLP ----
__global__ void __launch_bounds__(256) k_final(const float* __restrict__ pav,
        const float* __restrict__ Wo, const float* __restrict__ bo,
        const float* __restrict__ W1, const float* __restrict__ b1,
        const float* __restrict__ W2, const float* __restrict__ b2,
        float* __restrict__ out) {
    __shared__ float sp[HIDDEN];
    __shared__ float st[OUTD];
    int t = threadIdx.x;
    if (t < HIDDEN) {
        float a = bo[t];
        for (int c = 0; c < HIDDEN; c++) a = fmaf(pav[c], Wo[c * HIDDEN + t], a);
        sp[t] = a;
    }
    __syncthreads();
    {
        float a = b1[t];
        for (int c = 0; c < HIDDEN; c++) a = fmaf(sp[c], W1[c * OUTD + t], a);
        st[t] = fmaxf(a, 0.f);
    }
    __syncthreads();
    {
        float o = b2[t];
        for (int c = 0; c < OUTD; c++) o = fmaf(st[c], W2[c * OUTD + t], o);
        out[t] = o;
    }
}

extern "C" void kernel_launch(void* const* d_in, const int* in_sizes, int n_in,
                              void* d_out, int out_size, void* d_ws, size_t ws_size,
                              hipStream_t stream) {
    (void)n_in; (void)out_size; (void)ws_size;
    const float* x   = (const float*)d_in[0];
    const float* pos = (const float*)d_in[1];
    const float* lig = (const float*)d_in[2];
    const float* Wn  = (const float*)d_in[3];
    const float* bn  = (const float*)d_in[4];
    const float* Wq  = (const float*)d_in[5];
    const float* bq  = (const float*)d_in[6];
    const float* Wk  = (const float*)d_in[7];
    const float* bk  = (const float*)d_in[8];
    const float* Wv  = (const float*)d_in[9];
    const float* bv  = (const float*)d_in[10];
    const float* Wo  = (const float*)d_in[11];
    const float* bo  = (const float*)d_in[12];
    const float* W1  = (const float*)d_in[13];
    const float* b1  = (const float*)d_in[14];
    const float* W2  = (const float*)d_in[15];
    const float* b2  = (const float*)d_in[16];
    int M = in_sizes[2] / 3;

    char* ws = (char*)d_ws;
    float*          px  = (float*)(ws + OFF_PX);
    float*          py  = (float*)(ws + OFF_PY);
    float*          pz  = (float*)(ws + OFF_PZ);
    float*          sq  = (float*)(ws + OFF_SQ);
    float*          dl  = (float*)(ws + OFF_DL);
    int*            cnt = (int*)  (ws + OFF_CNT);
    int*            sel = (int*)  (ws + OFF_SEL);
    unsigned short* qpk = (unsigned short*)(ws + OFF_QPK);
    unsigned short* kpk = (unsigned short*)(ws + OFF_KPK);
    float*          vg  = (float*)(ws + OFF_V);
    float*          lp  = (float*)(ws + OFF_LP);
    float*          rl  = (float*)(ws + OFF_RL);
    float*          wp  = (float*)(ws + OFF_WP);
    float*          pav = (float*)(ws + OFF_PAV);

    hipMemsetAsync(ws + OFF_CNT, 0, (size_t)NPTS * 4, stream);
    hipMemsetAsync(ws + OFF_PAV, 0, (size_t)HIDDEN * 4, stream);

    hipLaunchKernelGGL(k_prep,     dim3(64),       dim3(256),  0, stream, pos, lig, M, px, py, pz, sq, dl);
    hipLaunchKernelGGL(k_neighbor, dim3(64, 32),   dim3(256),  0, stream, px, py, pz, sq, cnt);
    hipLaunchKernelGGL(k_select,   dim3(1),        dim3(1024), 0, stream, dl, cnt, sel);
    hipLaunchKernelGGL(k_qkv,      dim3(KSEL/8),   dim3(128),  0, stream, x, sel, Wn, bn, Wq, bq, Wk, bk, Wv, bv, qpk, kpk, vg);
    hipLaunchKernelGGL(k_attn_l,   dim3(4, 64, 8), dim3(256),  0, stream, qpk, kpk, lp);
    hipLaunchKernelGGL(k_rl,       dim3(NHEADS*KSEL/256), dim3(256), 0, stream, lp, rl);
    hipLaunchKernelGGL(k_attn_w,   dim3(4, 64, 8), dim3(256),  0, stream, qpk, kpk, rl, wp);
    hipLaunchKernelGGL(k_colsum,   dim3(32),       dim3(256),  0, stream, wp, vg, pav);
    hipLaunchKernelGGL(k_final,    dim3(1),        dim3(256),  0, stream, pav, Wo, bo, W1, b1, W2, b2, (float*)d_out);
}